// Round 8
// baseline (557.196 us; speedup 1.0000x reference)
//
#include <hip/hip_runtime.h>
#include <stdint.h>
#include <stddef.h>

// QuantizedColumnParallel: y[4096,16384] = x[4096,4096] @ (wq[16384,4096]*scale)^T + bias
// R8: B-fragments DIRECT global->register (B out of LDS: LDS pipe 1400->~900 cyc/tile),
// A stays LDS-staged (4 buffers, 64KB, proven swizzle). sched_group_barrier forces
// {VMEM 1, DS 1, MFMA 4} interleave so LDS/TA pipes run under the matrix-pipe drain
// (R4/R6/R7 all measured pipes SUMMING at ~3000 cyc/tile in lockstep schedules).

#define M_TOT 4096
#define N_TOT 16384
#define K_TOT 4096
#define NT    64          // K-tiles

typedef __attribute__((ext_vector_type(4))) int      v4i;
typedef __attribute__((ext_vector_type(8))) _Float16 f16x8;
typedef __attribute__((ext_vector_type(4))) float    f32x4;

#define GLOAD_LDS16(g, l) __builtin_amdgcn_global_load_lds(                  \
    (const __attribute__((address_space(1))) void*)(g),                      \
    (__attribute__((address_space(3))) void*)(l), 16, 0, 0)

// ---------------- conversion pre-passes ----------------

__global__ __launch_bounds__(256) void cvt_x_i8(const float* __restrict__ x,
                                                signed char* __restrict__ o,
                                                float* __restrict__ sx) {
  const int row = blockIdx.x;
  const int tid = threadIdx.x;
  const float* xr = x + (size_t)row * K_TOT;
  float4 v[4];
  float mx = 0.f;
#pragma unroll
  for (int j = 0; j < 4; ++j) {
    v[j] = ((const float4*)xr)[tid * 4 + j];
    mx = fmaxf(mx, fmaxf(fmaxf(fabsf(v[j].x), fabsf(v[j].y)),
                         fmaxf(fabsf(v[j].z), fabsf(v[j].w))));
  }
#pragma unroll
  for (int off = 32; off; off >>= 1) mx = fmaxf(mx, __shfl_xor(mx, off));
  __shared__ float wm[4];
  if ((tid & 63) == 0) wm[tid >> 6] = mx;
  __syncthreads();
  const float m4 = fmaxf(fmaxf(wm[0], wm[1]), fmaxf(wm[2], wm[3]));
  const float smax = fmaxf(m4, 1e-6f);
  const float inv  = 127.0f / smax;
  if (tid == 0) sx[row] = smax / 127.0f;
  int p[4];
#pragma unroll
  for (int j = 0; j < 4; ++j) {
    int q0 = (int)rintf(v[j].x * inv), q1 = (int)rintf(v[j].y * inv);
    int q2 = (int)rintf(v[j].z * inv), q3 = (int)rintf(v[j].w * inv);
    q0 = max(-127, min(127, q0)); q1 = max(-127, min(127, q1));
    q2 = max(-127, min(127, q2)); q3 = max(-127, min(127, q3));
    p[j] = (q0 & 255) | ((q1 & 255) << 8) | ((q2 & 255) << 16) | (q3 << 24);
  }
  ((int4*)(o + (size_t)row * K_TOT))[tid] = make_int4(p[0], p[1], p[2], p[3]);
}

__global__ __launch_bounds__(256) void cvt_w_i8(const int* __restrict__ w,
                                                signed char* __restrict__ o, int n16) {
  const int stride = gridDim.x * blockDim.x;
  for (int i = blockIdx.x * blockDim.x + threadIdx.x; i < n16; i += stride) {
    int p[4];
#pragma unroll
    for (int j = 0; j < 4; ++j) {
      int4 a = ((const int4*)w)[i * 4 + j];
      p[j] = (a.x & 255) | ((a.y & 255) << 8) | ((a.z & 255) << 16) | (a.w << 24);
    }
    ((int4*)o)[i] = make_int4(p[0], p[1], p[2], p[3]);
  }
}

// ---------------- i8 GEMM: A in LDS (4 bufs), B direct-to-reg ----------------

// Stage one 256x64-byte A region (16 KiB): 2 x global_load_lds(16B)/thread.
// LDS dest linear; XOR swizzle on GLOBAL source chunk (rule #21). Conflict-free
// verified R3/R4/R6/R7 (SQ_LDS_BANK_CONFLICT = 0).
__device__ __forceinline__ void stage_i8(const signed char* __restrict__ g,
                                         size_t kbyte, signed char* l, int tid) {
#pragma unroll
  for (int j = 0; j < 2; ++j) {
    const int ci  = j * 512 + tid;       // 0..1023 16B-chunks
    const int row = ci >> 2;             // 0..255
    const int sc  = (ci & 3) ^ ((row >> 1) & 3);
    GLOAD_LDS16(g + (size_t)row * K_TOT + kbyte + sc * 16, l + ci * 16);
  }
}

// Swizzled fragment read: row r, 16B chunk hi (0..3). 2-way aliasing = free.
__device__ __forceinline__ v4i fragi(const signed char* region, int r, int hi) {
  return *(const v4i*)(region + r * 64 + ((hi ^ ((r >> 1) & 3)) << 4));
}

#define BAR()  do { __builtin_amdgcn_s_barrier(); \
                    __builtin_amdgcn_sched_barrier(0); } while (0)

// B-fragments: wave reads 16 rows (lr selects row, hi selects 16B chunk);
// lanes {lr, lr+16, lr+32, lr+48} together consume each row's 64B fully.
#define LOAD_B(B, Bw, kb)                                                     \
  do {                                                                        \
    _Pragma("unroll")                                                         \
    for (int n = 0; n < 4; ++n)                                               \
      B[n] = *(const v4i*)((Bw) + (size_t)n * 16 * K_TOT + (kb));             \
  } while (0)

#define READ_A(A, At)                                                         \
  do {                                                                        \
    _Pragma("unroll")                                                         \
    for (int m = 0; m < 8; ++m) A[m] = fragi(At, wr * 128 + m * 16 + lr, hi); \
  } while (0)

// 8 groups of {1 VMEM, 1 DS_READ, 4 MFMA}: feeds LDS/TA pipes during MFMA drain.
// Masks (LLVM SchedGroupMask): VMEM=0x10|VMEM_READ=0x20, DS_READ=0x100, MFMA=0x8.
#define MFMA_TILE(A, B)                                                       \
  do {                                                                        \
    _Pragma("unroll")                                                         \
    for (int m = 0; m < 8; ++m) {                                             \
      __builtin_amdgcn_sched_group_barrier(0x30, 1, 0);                       \
      __builtin_amdgcn_sched_group_barrier(0x100, 1, 0);                      \
      __builtin_amdgcn_sched_group_barrier(0x8, 4, 0);                        \
      _Pragma("unroll")                                                       \
      for (int n = 0; n < 4; ++n)                                             \
        acc[m][n] = __builtin_amdgcn_mfma_i32_16x16x64_i8(A[m], B[n],         \
                                                          acc[m][n], 0, 0, 0);\
    }                                                                         \
  } while (0)

__global__ __launch_bounds__(512, 2) void gemm_i8(
    const signed char* __restrict__ A8, const signed char* __restrict__ B8,
    const float* __restrict__ sx, const float* __restrict__ scale_p,
    const float* __restrict__ bias, float* __restrict__ out)
{
  // A-only LDS: 4 buffers x 16 KiB = 64 KiB
  __shared__ __align__(16) signed char lds[4][16384];

  const int tid  = threadIdx.x;
  const int lane = tid & 63;
  const int wave = tid >> 6;
  const int wr = wave >> 2;            // 0..1 (M)
  const int wc = wave & 3;             // 0..3 (N)
  const int lr = lane & 15;
  const int hi = lane >> 4;

  // XCD-aware swizzle: 1024 wg, 8 XCDs, 128 contiguous per XCD; bm fast.
  const int bid = blockIdx.x;
  const int wg  = (bid & 7) * 128 + (bid >> 3);
  const int bm  = wg & 15;
  const int bn  = wg >> 4;
  const int arow0 = bm * 256;
  const int brow0 = bn * 256;

  const signed char* Ag = A8 + (size_t)arow0 * K_TOT;
  const signed char* Bw = B8 + (size_t)(brow0 + wc * 64 + lr) * K_TOT + hi * 16;

  v4i acc[8][4];
#pragma unroll
  for (int m = 0; m < 8; ++m)
#pragma unroll
    for (int n = 0; n < 4; ++n)
      acc[m][n] = (v4i){0, 0, 0, 0};

  v4i afA[8], afB[8], bA[4], bB[4];

  // ---- prologue: B(0) frags; stage A(0,1,2). vmcnt(2) => B0,A0,A1 landed, A2 flying.
  LOAD_B(bA, Bw, 0);
  stage_i8(Ag, 0,   &lds[0][0], tid);
  stage_i8(Ag, 64,  &lds[1][0], tid);
  stage_i8(Ag, 128, &lds[2][0], tid);
  asm volatile("s_waitcnt vmcnt(2)" ::: "memory");
  BAR();
  READ_A(afA, &lds[0][0]);

  for (int t = 0; t < NT; t += 2) {
    // ---- tile t: cur = {afA,bA}; prefetch {afB <- A(t+1), bB <- B(t+1)}; stage A(t+3)
    {
      if (t + 1 < NT) LOAD_B(bB, Bw, (size_t)(t + 1) * 64);
      if (t + 3 < NT) stage_i8(Ag, (size_t)(t + 3) * 64, &lds[(t + 3) & 3][0], tid);
      if (t + 1 < NT) READ_A(afB, &lds[(t + 1) & 3][0]);
      MFMA_TILE(afA, bA);
      // ledger old->young: A(t+2)[2], B(t+1)[4], A(t+3)[2]; vmcnt(2) => A(t+2),B(t+1) done.
      if (t + 3 < NT) asm volatile("s_waitcnt vmcnt(2)" ::: "memory");
      else            asm volatile("s_waitcnt vmcnt(0)" ::: "memory");
      BAR();
    }
    // ---- tile t+1: cur = {afB,bB}; prefetch {afA <- A(t+2), bA <- B(t+2)}; stage A(t+4)
    {
      if (t + 2 < NT) LOAD_B(bA, Bw, (size_t)(t + 2) * 64);
      if (t + 4 < NT) stage_i8(Ag, (size_t)(t + 4) * 64, &lds[(t + 4) & 3][0], tid);
      if (t + 2 < NT) READ_A(afA, &lds[(t + 2) & 3][0]);
      MFMA_TILE(afB, bB);
      if (t + 4 < NT) asm volatile("s_waitcnt vmcnt(2)" ::: "memory");
      else            asm volatile("s_waitcnt vmcnt(0)" ::: "memory");
      BAR();
    }
  }

  // ---- epilogue: y = acc * (sx[row]*scale) + bias.
  // C/D map (dtype-independent): col=lane&15, row=(lane>>4)*4+reg.
  const float s = scale_p[0];
  float bv[4];
#pragma unroll
  for (int n = 0; n < 4; ++n) bv[n] = bias[brow0 + wc * 64 + n * 16 + lr];
#pragma unroll
  for (int mi = 0; mi < 8; ++mi) {
    const int row0 = arow0 + wr * 128 + (mi >> 2) * 64 + (mi & 3) * 16 + hi * 4;
    float sc4[4];
#pragma unroll
    for (int j = 0; j < 4; ++j) sc4[j] = sx[row0 + j] * s;
#pragma unroll
    for (int n = 0; n < 4; ++n) {
      const int col = brow0 + wc * 64 + n * 16 + lr;
      const v4i v = acc[mi][n];
#pragma unroll
      for (int j = 0; j < 4; ++j)
        out[(size_t)(row0 + j) * N_TOT + col] = (float)v[j] * sc4[j] + bv[n];
    }
  }
}

// ---------------- fallback (no workspace): f16 DIRECT 128^2 kernel ----------------

__global__ __launch_bounds__(256) void gemm_direct(
    const float* __restrict__ Xf, const int* __restrict__ Wq,
    const float* __restrict__ scale_p, const float* __restrict__ bias,
    float* __restrict__ out)
{
  __shared__ _Float16 ldsA[128 * 64];
  __shared__ _Float16 ldsB[128 * 64];
  const int tid = threadIdx.x, lane = tid & 63, wave = tid >> 6;
  const int wr = wave >> 1, wc = wave & 1;
  const int bid = blockIdx.x;
  const int wg  = (bid & 7) * 512 + (bid >> 3);
  const int arow0 = (wg & 31) * 128, brow0 = (wg >> 5) * 128;
  f32x4 acc[4][4];
#pragma unroll
  for (int m = 0; m < 4; ++m)
#pragma unroll
    for (int n = 0; n < 4; ++n) acc[m][n] = (f32x4){0.f, 0.f, 0.f, 0.f};
  const int srow = tid >> 3, schunk = tid & 7;
  const int lr = lane & 15, hi = lane >> 4;
  for (int kt = 0; kt < K_TOT / 64; ++kt) {
    const size_t kbase = (size_t)kt * 64;
    __syncthreads();
#pragma unroll
    for (int i = 0; i < 4; ++i) {
      const int row = i * 32 + srow;
      const int p = schunk ^ (row & 7);
      const float* gx = Xf + (size_t)(arow0 + row) * K_TOT + kbase + schunk * 8;
      const int*   gw = Wq + (size_t)(brow0 + row) * K_TOT + kbase + schunk * 8;
      float4 x0 = ((const float4*)gx)[0];
      float4 x1 = ((const float4*)gx)[1];
      int4   w0 = ((const int4*)gw)[0];
      int4   w1 = ((const int4*)gw)[1];
      f16x8 ha = { (_Float16)x0.x, (_Float16)x0.y, (_Float16)x0.z, (_Float16)x0.w,
                   (_Float16)x1.x, (_Float16)x1.y, (_Float16)x1.z, (_Float16)x1.w };
      f16x8 hb = { (_Float16)w0.x, (_Float16)w0.y, (_Float16)w0.z, (_Float16)w0.w,
                   (_Float16)w1.x, (_Float16)w1.y, (_Float16)w1.z, (_Float16)w1.w };
      *(f16x8*)(ldsA + row * 64 + p * 8) = ha;
      *(f16x8*)(ldsB + row * 64 + p * 8) = hb;
    }
    __syncthreads();
#pragma unroll
    for (int s2 = 0; s2 < 2; ++s2) {
      f16x8 af2[4], bf2[4];
#pragma unroll
      for (int m = 0; m < 4; ++m) {
        const int r = wr * 64 + m * 16 + lr;
        af2[m] = *(const f16x8*)(ldsA + r * 64 + (((s2 * 4 + hi) ^ (r & 7)) * 8));
      }
#pragma unroll
      for (int n = 0; n < 4; ++n) {
        const int r = wc * 64 + n * 16 + lr;
        bf2[n] = *(const f16x8*)(ldsB + r * 64 + (((s2 * 4 + hi) ^ (r & 7)) * 8));
      }
#pragma unroll
      for (int m = 0; m < 4; ++m)
#pragma unroll
        for (int n = 0; n < 4; ++n)
          acc[m][n] = __builtin_amdgcn_mfma_f32_16x16x32_f16(af2[m], bf2[n], acc[m][n], 0, 0, 0);
    }
  }
  const float s = scale_p[0];
#pragma unroll
  for (int n = 0; n < 4; ++n) {
    const int col = brow0 + wc * 64 + n * 16 + lr;
    const float bvv = bias[col];
#pragma unroll
    for (int m = 0; m < 4; ++m) {
      const int row0 = arow0 + wr * 64 + m * 16 + hi * 4;
      const f32x4 v = acc[m][n];
#pragma unroll
      for (int j = 0; j < 4; ++j)
        out[(size_t)(row0 + j) * N_TOT + col] = v[j] * s + bvv;
    }
  }
}

// ---------------- launch ----------------

extern "C" void kernel_launch(void* const* d_in, const int* in_sizes, int n_in,
                              void* d_out, int out_size, void* d_ws, size_t ws_size,
                              hipStream_t stream) {
  const float* x     = (const float*)d_in[0];
  const int*   wq    = (const int*)d_in[1];
  const float* scale = (const float*)d_in[2];
  const float* bias  = (const float*)d_in[3];
  float*       out   = (float*)d_out;

  const size_t nA = (size_t)M_TOT * K_TOT;   // 16.7M
  const size_t nB = (size_t)N_TOT * K_TOT;   // 67.1M
  const size_t need = nA + nB + M_TOT * sizeof(float);  // ~84 MiB

  if (ws_size >= need) {
    signed char* A8 = (signed char*)d_ws;
    signed char* B8 = A8 + nA;
    float*       sx = (float*)(B8 + nB);
    cvt_x_i8<<<M_TOT, 256, 0, stream>>>(x, A8, sx);
    cvt_w_i8<<<2048, 256, 0, stream>>>(wq, B8, (int)(nB / 16));
    gemm_i8<<<(M_TOT / 256) * (N_TOT / 256), 512, 0, stream>>>(A8, B8, sx, scale, bias, out);
  } else {
    gemm_direct<<<(M_TOT / 128) * (N_TOT / 128), 256, 0, stream>>>(x, wq, scale, bias, out);
  }
}